// Round 1
// baseline (379.501 us; speedup 1.0000x reference)
//
#include <hip/hip_runtime.h>
#include <hip/hip_bf16.h>

// GemmRS: out[m,n] = sum_{w,k} A[w,m,k]*B[w,n,k]
// A: [8,8192,512] f32, B: [8,1024,512] f32, out: [8192,1024] f32
// Single GEMM, M=8192 N=1024 K_total=4096 (8 banks of 512).
// bf16 MFMA (16x16x32), 128x128 tile, BK=32, fused f32->bf16 convert at staging.

#define WS 8
#define MM 8192
#define KK 512
#define NN 1024
#define KTOT (WS * KK)  // 4096
#define BM 128
#define BN 128
#define BK 32

typedef __attribute__((ext_vector_type(8))) short short8;
typedef __attribute__((ext_vector_type(4))) short short4v;
typedef __attribute__((ext_vector_type(4))) float floatx4;

static __device__ inline short f2bf(float f) {
    union { __hip_bfloat16 h; short s; } u;
    u.h = __float2bfloat16(f);  // RNE
    return u.s;
}

__global__ __launch_bounds__(256, 2)
void gemm_rs_kernel(const float* __restrict__ A, const float* __restrict__ B,
                    float* __restrict__ C) {
    __shared__ short As[BM * BK];  // 8 KB
    __shared__ short Bs[BN * BK];  // 8 KB

    const int tid = threadIdx.x;
    const int m0 = blockIdx.y * BM;  // 64 tiles
    const int n0 = blockIdx.x * BN;  // 8 tiles

    const int wid  = tid >> 6;
    const int lane = tid & 63;
    const int wr   = wid >> 1;   // wave row (0..1) -> 64-row sub-tile
    const int wc   = wid & 1;    // wave col (0..1) -> 64-col sub-tile
    const int lm   = lane & 15;
    const int quad = lane >> 4;  // 0..3 -> k-slice of 8 for operands

    // staging: 1024 float4 slots per matrix (128 rows x 8 float4), 4 per thread
    floatx4 acc[4][4];
#pragma unroll
    for (int i = 0; i < 4; ++i)
#pragma unroll
        for (int j = 0; j < 4; ++j) acc[i][j] = (floatx4)0.f;

    for (int kt = 0; kt < KTOT; kt += BK) {
        const int w  = kt >> 9;          // rank bank (uniform)
        const int kk = kt & (KK - 1);    // offset inside bank (uniform)
        const float* Aw = A + (size_t)w * MM * KK;
        const float* Bw = B + (size_t)w * NN * KK;

        __syncthreads();  // previous iter's LDS reads done
#pragma unroll
        for (int i = 0; i < 4; ++i) {
            const int idx = i * 256 + tid;
            const int row = idx >> 3;
            const int c4  = (idx & 7) * 4;
            float4 av = *(const float4*)&Aw[(size_t)(m0 + row) * KK + kk + c4];
            float4 bv = *(const float4*)&Bw[(size_t)(n0 + row) * KK + kk + c4];
            short4v a4 = { f2bf(av.x), f2bf(av.y), f2bf(av.z), f2bf(av.w) };
            short4v b4 = { f2bf(bv.x), f2bf(bv.y), f2bf(bv.z), f2bf(bv.w) };
            *(short4v*)&As[row * BK + c4] = a4;
            *(short4v*)&Bs[row * BK + c4] = b4;
        }
        __syncthreads();

        short8 af[4], bfr[4];
#pragma unroll
        for (int i = 0; i < 4; ++i)
            af[i] = *(const short8*)&As[(wr * 64 + i * 16 + lm) * BK + quad * 8];
#pragma unroll
        for (int j = 0; j < 4; ++j)
            bfr[j] = *(const short8*)&Bs[(wc * 64 + j * 16 + lm) * BK + quad * 8];
#pragma unroll
        for (int i = 0; i < 4; ++i)
#pragma unroll
            for (int j = 0; j < 4; ++j)
                acc[i][j] = __builtin_amdgcn_mfma_f32_16x16x32_bf16(
                    af[i], bfr[j], acc[i][j], 0, 0, 0);
    }

    // epilogue: C/D layout col = lane&15 (n), row = quad*4 + r (m)  [m89-verified]
#pragma unroll
    for (int i = 0; i < 4; ++i) {
#pragma unroll
        for (int j = 0; j < 4; ++j) {
            const int n = n0 + wc * 64 + j * 16 + lm;
#pragma unroll
            for (int r = 0; r < 4; ++r) {
                const int m = m0 + wr * 64 + i * 16 + quad * 4 + r;
                C[(size_t)m * NN + n] = acc[i][j][r];
            }
        }
    }
}

extern "C" void kernel_launch(void* const* d_in, const int* in_sizes, int n_in,
                              void* d_out, int out_size, void* d_ws, size_t ws_size,
                              hipStream_t stream) {
    const float* A = (const float*)d_in[0];  // [8,8192,512]
    const float* B = (const float*)d_in[1];  // [8,1024,512]
    float* C = (float*)d_out;                // [8192,1024] (== [8,1024,1024])

    dim3 grid(NN / BN, MM / BM);  // (8, 64)
    dim3 block(256);
    gemm_rs_kernel<<<grid, block, 0, stream>>>(A, B, C);
}

// Round 2
// 299.883 us; speedup vs baseline: 1.2655x; 1.2655x over previous
//
#include <hip/hip_runtime.h>
#include <hip/hip_bf16.h>

// GemmRS: out[m,n] = sum_{w,k} A[w,m,k]*B[w,n,k]
// A: [8,8192,512] f32, B: [8,1024,512] f32, out: [8192,1024] f32.
// Phase 1: convert A,B -> bf16 in d_ws (needs 72 MB; fallback below if not).
// Phase 2: bf16 MFMA GEMM, BM=128 BN=64 BK=64, grid 1024 (4 blocks/CU),
//          global_load_lds width=16 staging, XOR-swizzled LDS segments.

#define WS 8
#define MM 8192
#define KK 512
#define NN 1024
#define KTOT (WS * KK)  // 4096
#define BM 128
#define BN 64
#define BK 64

#define A_ELEMS ((size_t)WS * MM * KK)  // 33,554,432
#define B_ELEMS ((size_t)WS * NN * KK)  //  4,194,304
#define WS_NEEDED ((A_ELEMS + B_ELEMS) * 2)  // 75,497,472 bytes

typedef __attribute__((ext_vector_type(8))) short short8;
typedef __attribute__((ext_vector_type(4))) short short4v;
typedef __attribute__((ext_vector_type(4))) float floatx4;

static __device__ inline short f2bf(float f) {
    union { __hip_bfloat16 h; short s; } u;
    u.h = __float2bfloat16(f);  // RNE
    return u.s;
}

static __device__ inline void glds16(const short* g, short* l) {
    // generic->as(1): same 64-bit VA; generic->as(3): low 32 bits are the LDS
    // offset (shared-aperture layout) — the CK-style uintptr_t cast.
    __builtin_amdgcn_global_load_lds(
        (const __attribute__((address_space(1))) unsigned int*)(uintptr_t)g,
        (__attribute__((address_space(3))) unsigned int*)(uintptr_t)l,
        16, 0, 0);
}

// ---------------- Phase 1: f32 -> bf16 convert (streaming) ----------------
// 8 elems/thread. A: 16384 blocks, B: 2048 blocks. One launch, 18432 blocks.
#define CVT_ABLOCKS 16384
#define CVT_NBLOCKS 18432

__global__ __launch_bounds__(256)
void cvt_f32_bf16(const float* __restrict__ A, const float* __restrict__ B,
                  short* __restrict__ Abf, short* __restrict__ Bbf) {
    const float* src;
    short* dst;
    size_t base;
    if (blockIdx.x < CVT_ABLOCKS) {
        src = A; dst = Abf;
        base = ((size_t)blockIdx.x * 256 + threadIdx.x) * 8;
    } else {
        src = B; dst = Bbf;
        base = ((size_t)(blockIdx.x - CVT_ABLOCKS) * 256 + threadIdx.x) * 8;
    }
    float4 v0 = *(const float4*)(src + base);
    float4 v1 = *(const float4*)(src + base + 4);
    short8 o = { f2bf(v0.x), f2bf(v0.y), f2bf(v0.z), f2bf(v0.w),
                 f2bf(v1.x), f2bf(v1.y), f2bf(v1.z), f2bf(v1.w) };
    *(short8*)(dst + base) = o;
}

// ---------------- Phase 2: bf16 GEMM ----------------
// 4 waves: wr in {0,1} (64 rows each), wc in {0,1} (32 cols each).
// Per wave: 4 m-frags x 2 n-frags x (BK/32=2) -> 16 MFMA/iter.
__global__ __launch_bounds__(256, 4)
void gemm_bf16_rs(const short* __restrict__ Abf, const short* __restrict__ Bbf,
                  float* __restrict__ C) {
    __shared__ short As[BM * BK];  // 16 KB
    __shared__ short Bs[BN * BK];  // 8 KB

    const int tid  = threadIdx.x;
    const int lane = tid & 63;
    const int wid  = tid >> 6;
    const int m0 = blockIdx.y * BM;  // grid.y = 64
    const int n0 = blockIdx.x * BN;  // grid.x = 16
    const int wr = wid >> 1, wc = wid & 1;
    const int lm = lane & 15, quad = lane >> 4;

    // Staging geometry: chunk = 64 lanes x 16B = 8 rows x 8 segs (seg = 8 bf16).
    // lane -> (row_in_chunk = lane>>3, seg = lane&7). Swizzle: source seg is
    // (lane&7) ^ (row&7); row&7 == lane>>3 for all chunks here.
    const int lrow = lane >> 3;
    const int ss   = (lane & 7) ^ lrow;  // swizzled source segment

    size_t gA[4], gB[2];
#pragma unroll
    for (int t = 0; t < 4; ++t)
        gA[t] = (size_t)(m0 + wid * 32 + t * 8 + lrow) * KK + ss * 8;
#pragma unroll
    for (int t = 0; t < 2; ++t)
        gB[t] = (size_t)(n0 + wid * 16 + t * 8 + lrow) * KK + ss * 8;

    floatx4 acc[4][2];
#pragma unroll
    for (int i = 0; i < 4; ++i)
#pragma unroll
        for (int j = 0; j < 2; ++j) acc[i][j] = (floatx4)0.f;

    for (int kt = 0; kt < KTOT; kt += BK) {
        const int w  = kt >> 9;         // rank bank (uniform)
        const int kk = kt & (KK - 1);   // offset inside bank (uniform)
        const short* Aw = Abf + (size_t)w * MM * KK + kk;
        const short* Bw = Bbf + (size_t)w * NN * KK + kk;

        __syncthreads();  // prior iter's LDS reads done before overwrite
#pragma unroll
        for (int t = 0; t < 4; ++t)
            glds16(Aw + gA[t], &As[(wid * 4 + t) * 512 + lane * 8]);
#pragma unroll
        for (int t = 0; t < 2; ++t)
            glds16(Bw + gB[t], &Bs[(wid * 2 + t) * 512 + lane * 8]);
        __syncthreads();  // drains vmcnt (glds) per barrier semantics

        short8 af[2][4], bfr[2][2];
#pragma unroll
        for (int kc = 0; kc < 2; ++kc) {
#pragma unroll
            for (int i = 0; i < 4; ++i) {
                const int row = wr * 64 + i * 16 + lm;
                const int sa  = (kc * 4 + quad) ^ (lm & 7);
                af[kc][i] = *(const short8*)&As[row * BK + sa * 8];
            }
#pragma unroll
            for (int j = 0; j < 2; ++j) {
                const int row = wc * 32 + j * 16 + lm;
                const int sb  = (kc * 4 + quad) ^ (lm & 7);
                bfr[kc][j] = *(const short8*)&Bs[row * BK + sb * 8];
            }
        }
#pragma unroll
        for (int kc = 0; kc < 2; ++kc)
#pragma unroll
            for (int i = 0; i < 4; ++i)
#pragma unroll
                for (int j = 0; j < 2; ++j)
                    acc[i][j] = __builtin_amdgcn_mfma_f32_16x16x32_bf16(
                        af[kc][i], bfr[kc][j], acc[i][j], 0, 0, 0);
    }

    // Epilogue: C/D layout col = lane&15 (n), row = quad*4 + r (m) [m89]
#pragma unroll
    for (int i = 0; i < 4; ++i)
#pragma unroll
        for (int j = 0; j < 2; ++j) {
            const int n = n0 + wc * 32 + j * 16 + lm;
#pragma unroll
            for (int r = 0; r < 4; ++r) {
                const int m = m0 + wr * 64 + i * 16 + quad * 4 + r;
                C[(size_t)m * NN + n] = acc[i][j][r];
            }
        }
}

// ---------------- Fallback (round-1 fused kernel, ws too small) ----------------
__global__ __launch_bounds__(256, 2)
void gemm_rs_fused(const float* __restrict__ A, const float* __restrict__ B,
                   float* __restrict__ C) {
    __shared__ short As[128 * 32];
    __shared__ short Bs[128 * 32];
    const int tid = threadIdx.x;
    const int m0 = blockIdx.y * 128;
    const int n0 = blockIdx.x * 128;
    const int wid = tid >> 6, lane = tid & 63;
    const int wr = wid >> 1, wc = wid & 1;
    const int lm = lane & 15, quad = lane >> 4;
    floatx4 acc[4][4];
#pragma unroll
    for (int i = 0; i < 4; ++i)
#pragma unroll
        for (int j = 0; j < 4; ++j) acc[i][j] = (floatx4)0.f;
    for (int kt = 0; kt < KTOT; kt += 32) {
        const int w = kt >> 9, kk = kt & (KK - 1);
        const float* Aw = A + (size_t)w * MM * KK;
        const float* Bw = B + (size_t)w * NN * KK;
        __syncthreads();
#pragma unroll
        for (int i = 0; i < 4; ++i) {
            const int idx = i * 256 + tid;
            const int row = idx >> 3;
            const int c4 = (idx & 7) * 4;
            float4 av = *(const float4*)&Aw[(size_t)(m0 + row) * KK + kk + c4];
            float4 bv = *(const float4*)&Bw[(size_t)(n0 + row) * KK + kk + c4];
            short4v a4 = { f2bf(av.x), f2bf(av.y), f2bf(av.z), f2bf(av.w) };
            short4v b4 = { f2bf(bv.x), f2bf(bv.y), f2bf(bv.z), f2bf(bv.w) };
            *(short4v*)&As[row * 32 + c4] = a4;
            *(short4v*)&Bs[row * 32 + c4] = b4;
        }
        __syncthreads();
        short8 af[4], bfr[4];
#pragma unroll
        for (int i = 0; i < 4; ++i)
            af[i] = *(const short8*)&As[(wr * 64 + i * 16 + lm) * 32 + quad * 8];
#pragma unroll
        for (int j = 0; j < 4; ++j)
            bfr[j] = *(const short8*)&Bs[(wc * 64 + j * 16 + lm) * 32 + quad * 8];
#pragma unroll
        for (int i = 0; i < 4; ++i)
#pragma unroll
            for (int j = 0; j < 4; ++j)
                acc[i][j] = __builtin_amdgcn_mfma_f32_16x16x32_bf16(
                    af[i], bfr[j], acc[i][j], 0, 0, 0);
    }
#pragma unroll
    for (int i = 0; i < 4; ++i)
#pragma unroll
        for (int j = 0; j < 4; ++j) {
            const int n = n0 + wc * 64 + j * 16 + lm;
#pragma unroll
            for (int r = 0; r < 4; ++r) {
                const int m = m0 + wr * 64 + i * 16 + quad * 4 + r;
                C[(size_t)m * NN + n] = acc[i][j][r];
            }
        }
}

extern "C" void kernel_launch(void* const* d_in, const int* in_sizes, int n_in,
                              void* d_out, int out_size, void* d_ws, size_t ws_size,
                              hipStream_t stream) {
    const float* A = (const float*)d_in[0];  // [8,8192,512]
    const float* B = (const float*)d_in[1];  // [8,1024,512]
    float* C = (float*)d_out;                // [8192,1024]

    if (ws_size >= WS_NEEDED) {
        short* Abf = (short*)d_ws;
        short* Bbf = Abf + A_ELEMS;
        cvt_f32_bf16<<<CVT_NBLOCKS, 256, 0, stream>>>(A, B, Abf, Bbf);
        dim3 grid(NN / BN, MM / BM);  // (16, 64) = 1024 blocks
        gemm_bf16_rs<<<grid, 256, 0, stream>>>(Abf, Bbf, C);
    } else {
        dim3 grid(NN / 128, MM / 128);  // (8, 64)
        gemm_rs_fused<<<grid, 256, 0, stream>>>(A, B, C);
    }
}